// Round 12
// baseline (988.993 us; speedup 1.0000x reference)
//
#include <hip/hip_runtime.h>
#include <hip/hip_bf16.h>
#include <hip/hip_fp8.h>
#include <stdint.h>

#define E_ 100
#define L_ 6
#define ROWS 128            // 8 waves * 16 rows
#define THREADS 512
#define HSTRB 128           // Hlds row stride in BYTES (8 chunks of 16B), fp8 elems

// W fragment image offsets (in BYTES) — fp8 e4m3
#define OFF_MAIN 0          // nt 0..5, kk 0..2, g 0..3 : 72 frags * 512 B
#define OFF_NT6  36864      // nt=6,  kk 0..2, g 0..3 : 12 frags * 128 B (cols 0..3)
#define OFF_K3   38400      // nt 0..6, g 0..3 (k=96..111): 28 half-frags * 256 B
#define OFF_ZERO 45568      // 8 zero bytes
#define WF_TOTAL 45576
#define OFF_WOUT 45576      // kk0..2: 3*512B, then kk3 half: 256 B
#define WS_TOTAL 47368      // Wout now staged into LDS too (contiguous after WF)

typedef __attribute__((ext_vector_type(4))) float f32x4;
typedef __attribute__((ext_vector_type(2))) float pf2;

#define L2E 1.44269504088896340736f
#define LN2 0.69314718055994530942f

#define E2(x) __builtin_amdgcn_exp2f(x)
#define LOG2(x) __builtin_amdgcn_logf(x)
#define RCP(x) __builtin_amdgcn_rcpf(x)

__device__ __forceinline__ unsigned char f2q(float x) {   // f32 -> OCP e4m3fn
  __hip_fp8_e4m3 q(x);
  return (unsigned char)q.__x;
}

__device__ __forceinline__ float rng_u(uint32_t id) {
  uint64_t x = (uint64_t)id;
  x += 0x9E3779B97F4A7C15ull;
  x = (x ^ (x >> 30)) * 0xBF58476D1CE4E5B9ull;
  x = (x ^ (x >> 27)) * 0x94D049BB133111EBull;
  x ^= (x >> 31);
  return ((float)(uint32_t)(x >> 40) + 0.5f) * (1.0f / 16777216.0f);
}

// gate scale: i,f,o rows -log2(e); g rows +2*log2(e)
__device__ __forceinline__ float gsf(int g) { return (g == 2) ? (2.f * L2E) : (-L2E); }

__device__ float wval(int n, int k, const float* w_hh, const float* w_ih,
                      const float* emb, const float* b_ih, const float* b_hh) {
  if (k < 100) return w_hh[n * 100 + k];
  if (k < 110) {
    int t = k - 100;
    float s = 0.f;
    for (int m = 0; m < 100; ++m) s += emb[t * 100 + m] * w_ih[n * 100 + m];
    return s;
  }
  if (k == 110) return b_ih[n] + b_hh[n];
  return 0.f;
}

__global__ void prep_kernel(const float* __restrict__ emb, const float* __restrict__ w_ih,
                            const float* __restrict__ w_hh, const float* __restrict__ b_ih,
                            const float* __restrict__ b_hh, const float* __restrict__ w_out,
                            const float* __restrict__ b_out,
                            unsigned char* __restrict__ ws, float* __restrict__ tail,
                            float draws) {
  int id = blockIdx.x * 256 + threadIdx.x;
  if (id == 0) tail[2] = draws;
  if (id >= WS_TOTAL) return;
  float v = 0.f;
  if (id < OFF_NT6) {                       // MAIN: nt<6, kk<3 (pure w_hh)
    int frag = id >> 9, w = id & 511, lane = w >> 3, j = w & 7;
    int nt = frag / 12, rem = frag % 12, kk = rem >> 2, g = rem & 3;
    int col = lane & 15, grp = lane >> 4;
    int n = g * 100 + nt * 16 + col;
    int k = kk * 32 + grp * 8 + j;
    v = w_hh[n * 100 + k] * gsf(g);
  } else if (id < OFF_K3) {                 // NT6 compressed: cols 0..3
    int t = id - OFF_NT6;
    int frag = t >> 7, w = t & 127, i = w >> 3, j = w & 7;
    int kk = frag >> 2, g = frag & 3;
    int grp = i >> 2, colc = i & 3;
    int n = g * 100 + 96 + colc;
    int k = kk * 32 + grp * 8 + j;
    v = w_hh[n * 100 + k] * gsf(g);
  } else if (id < OFF_ZERO) {               // K3 half-frags: k = 96..111
    int t = id - OFF_K3;
    int frag = t >> 8, w = t & 255, i = w >> 3, j = w & 7;
    int nt = frag >> 2, g = frag & 3;
    int col = i & 15, g2 = i >> 4;
    int nl = nt * 16 + col;
    int k = 96 + g2 * 8 + j;
    v = (nl < 100) ? wval(g * 100 + nl, k, w_hh, w_ih, emb, b_ih, b_hh) * gsf(g) : 0.f;
  } else if (id < WF_TOTAL) {               // zero block
    v = 0.f;
  } else if (id < OFF_WOUT + 1536) {        // Wout kk0..2 (scaled by log2 e)
    int t = id - OFF_WOUT;
    int kk = t >> 9, w = t & 511, lane = w >> 3, j = w & 7;
    int tt = lane & 15, grp = lane >> 4;
    int k = kk * 32 + grp * 8 + j;
    v = (tt < 10) ? w_out[tt * 100 + k] * L2E : 0.f;
  } else {                                  // Wout kk3 half-frag
    int t = id - (OFF_WOUT + 1536);
    int i = t >> 3, j = t & 7;
    int tt = i & 15, g2 = i >> 4;
    int k = 96 + g2 * 8 + j;
    if (tt < 10) {
      if (k < 100) v = w_out[tt * 100 + k] * L2E;
      else if (k == 110) v = b_out[tt] * L2E;
    }
  }
  ws[id] = f2q(v);
}

// (512,3): allocator law (R4/R9/R10/R11) gives arch-VGPR target 512/6≈85; with ~20
// accumulator regs total stays <=128 bucket -> 4 waves/SIMD. 2 blocks/CU via 69.4KB LDS.
__global__ void __launch_bounds__(THREADS, 3)
lstm_kernel(const float* __restrict__ h_t,
            const unsigned char* __restrict__ ws,
            const int* __restrict__ testing_p,
            float* __restrict__ out, float* __restrict__ tail) {
  __shared__ __align__(16) unsigned char Wlds[WS_TOTAL + 8];   // 47376 B (incl. Wout frags)
  __shared__ __align__(16) unsigned char Hlds[ROWS * HSTRB];   // 16384 B
  __shared__ float Llds[ROWS * 11];                            // 5632 B  -> total ~69.4 KB

  const int tid = threadIdx.x;
  const int lane = tid & 63;
  const int w = tid >> 6;                    // 8 waves
  const int col = lane & 15;
  const int grp = lane >> 4;
  const int wrow0 = w * 16;                  // each wave owns 16 rows
  const int rowbase0 = blockIdx.x * ROWS;
  const int tst = *testing_p;

  const f32x4 z4 = {0.f, 0.f, 0.f, 0.f};
  const unsigned char Q1 = 0x38;             // fp8 e4m3 1.0

  // ---- stage W + Wout fragments (linear 8B copy; 47368/8 = 5921) ----
  for (int i = tid; i < WS_TOTAL / 8; i += THREADS)
    *(long long*)&Wlds[i * 8] = ((const long long*)ws)[i];

  // ---- stage h_t -> fp8, swizzled 128B rows ----
  for (int i = tid; i < ROWS * 25; i += THREADS) {
    int r = i / 25, ch = i % 25;
    const float4 v = *(const float4*)(h_t + (size_t)(rowbase0 + r) * E_ + ch * 4);
    uchar4 pk = make_uchar4(f2q(v.x), f2q(v.y), f2q(v.z), f2q(v.w));
    *(uchar4*)&Hlds[r * HSTRB + (((ch >> 2) ^ (r & 7)) << 4) + (ch & 3) * 4] = pk;
  }
  // ---- onehot(tok=0) + bias init (k=100..111, bytes 4..15 of logical chunk 6) ----
  if (tid < ROWS) {
    int r = tid;
    int base = r * HSTRB + ((6 ^ (r & 7)) << 4);
    *(uchar4*)&Hlds[base + 4]  = make_uchar4(Q1, 0, 0, 0);    // k=100..103
    *(uchar4*)&Hlds[base + 8]  = make_uchar4(0, 0, 0, 0);     // k=104..107
    *(uchar4*)&Hlds[base + 12] = make_uchar4(0, 0, Q1, 0);    // k=108,109,bias,pad
  }

  __syncthreads();
  // Waves fully independent (each owns rows [wrow0, wrow0+16)).

  auto ldA = [&](int kk) -> long long {
    int row = wrow0 + col;
    long long v;
    if (kk < 3) {
      int chunk = 2 * kk + (grp >> 1);
      v = *(const long long*)&Hlds[row * HSTRB + ((chunk ^ (row & 7)) << 4) + (grp & 1) * 8];
    } else {
      v = *(const long long*)&Hlds[row * HSTRB + ((6 ^ (row & 7)) << 4) + (grp & 1) * 8];
      if (grp >= 2) v = 0LL;   // upper K half of last frag zero (B mirrors)
    }
    return v;
  };

  long long a[4];
#pragma unroll
  for (int kk = 0; kk < 3; ++kk) a[kk] = ldA(kk);

  float cst[7][4] = {};   // c-state in 2*log2(e) scale (f32 registers)
  float ent_acc = 0.f, match_acc = 0.f;

#pragma unroll 1
  for (int step = 0; step < L_; ++step) {
    a[3] = ldA(3);   // onehot chunk refreshed

#pragma unroll
    for (int nt = 0; nt < 7; ++nt) {
      f32x4 acc[4];
#pragma unroll
      for (int g = 0; g < 4; ++g) acc[g] = z4;

#pragma unroll
      for (int kk = 0; kk < 3; ++kk) {
        long long b[4];
#pragma unroll
        for (int g = 0; g < 4; ++g) {
          if (nt < 6) {
            b[g] = *(const long long*)&Wlds[OFF_MAIN + ((nt * 3 + kk) * 4 + g) * 512 + lane * 8];
          } else {
            int addr = (col < 4) ? (OFF_NT6 + (kk * 4 + g) * 128 + (grp * 4 + col) * 8)
                                 : OFF_ZERO;
            b[g] = *(const long long*)&Wlds[addr];
          }
        }
#pragma unroll
        for (int g = 0; g < 4; ++g)
          acc[g] = __builtin_amdgcn_mfma_f32_16x16x32_fp8_fp8(a[kk], b[g], acc[g], 0, 0, 0);
      }
      // kk=3 (k=96..111): half-frags, lanes>=32 mirror (A zeroed there)
#pragma unroll
      for (int g = 0; g < 4; ++g) {
        long long b3 = *(const long long*)&Wlds[OFF_K3 + (nt * 4 + g) * 256 + (lane & 31) * 8];
        acc[g] = __builtin_amdgcn_mfma_f32_16x16x32_fp8_fp8(a[3], b3, acc[g], 0, 0, 0);
      }

      // ---- LSTM elementwise, packed f32 pairs across rr ----
      const bool evalid = (nt < 6) || (col < 4);   // e = nt*16+col < 100
      const pf2 one2 = {1.f, 1.f};
#pragma unroll
      for (int p = 0; p < 2; ++p) {
        const int r0 = 2 * p, r1 = 2 * p + 1;
        pf2 ei, ef, eg, eo, ct;
        ei.x = E2(acc[0][r0]); ei.y = E2(acc[0][r1]);
        ef.x = E2(acc[1][r0]); ef.y = E2(acc[1][r1]);
        eg.x = E2(acc[2][r0]); eg.y = E2(acc[2][r1]);
        eo.x = E2(acc[3][r0]); eo.y = E2(acc[3][r1]);
        ct.x = cst[nt][r0];    ct.y = cst[nt][r1];
        pf2 pi1 = one2 + ei, pf1 = one2 + ef, eg1 = eg + one2;
        pf2 egm2 = eg * (2.f * L2E) - (2.f * L2E);
        pf2 t1 = pi1 * eg1;
        pf2 num = ct * t1 + egm2 * pf1;
        pf2 den = pf1 * t1;
        pf2 cn;
        cn.x = num.x * RCP(den.x); cn.y = num.y * RCP(den.y);
        cst[nt][r0] = cn.x; cst[nt][r1] = cn.y;
        pf2 ec; ec.x = E2(cn.x); ec.y = E2(cn.y);
        pf2 d2 = (ec + one2) * (one2 + eo);
        pf2 hn;
        hn.x = (ec.x - 1.f) * RCP(d2.x); hn.y = (ec.y - 1.f) * RCP(d2.y);
        if (evalid) {
          int row0 = wrow0 + grp * 4 + r0;
          int row1 = row0 + 1;
          Hlds[row0 * HSTRB + ((nt ^ (row0 & 7)) << 4) + col] = f2q(hn.x);
          Hlds[row1 * HSTRB + ((nt ^ (row1 & 7)) << 4) + col] = f2q(hn.y);
        }
      }
    } // nt

    // full A reload (serves logits now + next step's gates)
#pragma unroll
    for (int kk = 0; kk < 4; ++kk) a[kk] = ldA(kk);

    // Wout frags from LDS (transient regs, freed after logits)
    f32x4 accl = z4;
#pragma unroll
    for (int kk = 0; kk < 3; ++kk) {
      long long bo = *(const long long*)&Wlds[OFF_WOUT + kk * 512 + lane * 8];
      accl = __builtin_amdgcn_mfma_f32_16x16x32_fp8_fp8(a[kk], bo, accl, 0, 0, 0);
    }
    {
      long long bo3 = *(const long long*)&Wlds[OFF_WOUT + 1536 + (lane & 31) * 8];
      accl = __builtin_amdgcn_mfma_f32_16x16x32_fp8_fp8(a[3], bo3, accl, 0, 0, 0);
    }

    // logits (log2-scaled) -> Llds
    if (col < 10) {
#pragma unroll
      for (int rr = 0; rr < 4; ++rr)
        Llds[(wrow0 + grp * 4 + rr) * 11 + col] = accl[rr];
    }

    // ---- scalar per-row softmax / argmax / CDF-sample / entropy ----
    if (lane < 16) {
      const int r = wrow0 + lane;
      const int growf = rowbase0 + r;
      float lg[10];
#pragma unroll
      for (int t = 0; t < 10; ++t) lg[t] = Llds[r * 11 + t];

      float m = lg[0]; int am = 0;
#pragma unroll
      for (int t = 1; t < 10; ++t) if (lg[t] > m) { m = lg[t]; am = t; }
      float S = 0.f, dp = 0.f;
#pragma unroll
      for (int t = 0; t < 10; ++t) {
        float z = lg[t] - m;
        float ev = E2(z);
        lg[t] = ev; S += ev; dp = fmaf(ev, z, dp);
      }
      float rS = RCP(S);
      ent_acc += (LOG2(S) - dp * rS) * LN2;

      int tok;
      if (tst) tok = am;
      else {
        float u = rng_u((uint32_t)growf * 6u + (uint32_t)step);
        float target = u * S;
        float cum = 0.f; int cnt = 0;
#pragma unroll
        for (int t = 0; t < 9; ++t) { cum += lg[t]; cnt += (cum < target) ? 1 : 0; }
        tok = cnt;
      }
      out[(size_t)growf * L_ + step] = (float)tok;
      match_acc += (tok == am) ? 1.f : 0.f;

      int base = r * HSTRB + ((6 ^ (r & 7)) << 4);
      *(uchar4*)&Hlds[base + 4]  = make_uchar4(tok==0?Q1:0, tok==1?Q1:0, tok==2?Q1:0, tok==3?Q1:0);
      *(uchar4*)&Hlds[base + 8]  = make_uchar4(tok==4?Q1:0, tok==5?Q1:0, tok==6?Q1:0, tok==7?Q1:0);
      *(uchar4*)&Hlds[base + 12] = make_uchar4(tok==8?Q1:0, tok==9?Q1:0, Q1, 0);
    }
  } // step

  // ---- block reduce: entropy + matches (2 atomics per block) ----
#pragma unroll
  for (int d2 = 1; d2 < 16; d2 <<= 1) {
    ent_acc += __shfl_xor(ent_acc, d2);
    match_acc += __shfl_xor(match_acc, d2);
  }
  __syncthreads();
  float* red = Llds;
  if (lane == 0) { red[w * 2] = ent_acc; red[w * 2 + 1] = match_acc; }
  __syncthreads();
  if (tid == 0) {
    float es = 0.f, ms = 0.f;
#pragma unroll
    for (int i = 0; i < 8; ++i) { es += red[i * 2]; ms += red[i * 2 + 1]; }
    atomicAdd(&tail[0], es);
    atomicAdd(&tail[1], ms);
  }
}

extern "C" void kernel_launch(void* const* d_in, const int* in_sizes, int n_in,
                              void* d_out, int out_size, void* d_ws, size_t ws_size,
                              hipStream_t stream) {
  const float* h_t   = (const float*)d_in[0];
  const float* emb   = (const float*)d_in[1];
  const float* w_ih  = (const float*)d_in[2];
  const float* w_hh  = (const float*)d_in[3];
  const float* b_ih  = (const float*)d_in[4];
  const float* b_hh  = (const float*)d_in[5];
  const float* w_out = (const float*)d_in[6];
  const float* b_out = (const float*)d_in[7];
  const int* testing = (const int*)d_in[8];
  float* out = (float*)d_out;
  const int B = in_sizes[0] / E_;
  float* tail = out + (size_t)B * L_;

  unsigned char* ws = (unsigned char*)d_ws;

  hipMemsetAsync(tail, 0, 2 * sizeof(float), stream);

  prep_kernel<<<(WS_TOTAL + 255) / 256, 256, 0, stream>>>(
      emb, w_ih, w_hh, b_ih, b_hh, w_out, b_out, ws, tail,
      (float)((long long)B * L_));

  lstm_kernel<<<B / ROWS, THREADS, 0, stream>>>(h_t, ws, testing, out, tail);
}

// Round 13
// 310.364 us; speedup vs baseline: 3.1866x; 3.1866x over previous
//
#include <hip/hip_runtime.h>
#include <hip/hip_bf16.h>
#include <stdint.h>

#define E_ 100
#define L_ 6
#define ROWS 256
#define THREADS 512
#define HSTR 128            // Hlds row stride in shorts (256 B, 16 chunks)

// W fragment image offsets (in shorts)
#define OFF_MAIN 0          // nt 0..5, kk 0..2, g 0..3 : 72 frags * 512 shorts
#define OFF_NT6  36864      // nt=6,  kk 0..2, g 0..3 : 12 frags * 128 shorts (cols 0..3)
#define OFF_K3   38400      // nt 0..6, g 0..3 (k=96..111): 28 frags * 256 shorts (half)
#define OFF_ZERO 45568      // 8 zero shorts
#define WF_TOTAL 45576
#define OFF_WOUT 45576      // kk0..2: 3*512, then kk3 half: 256 shorts
#define WS_TOTAL 47368

typedef __attribute__((ext_vector_type(8))) short short8;
typedef __attribute__((ext_vector_type(4))) float f32x4;
typedef __attribute__((ext_vector_type(2))) float pf2;   // packed f32 pair -> v_pk_* on gfx950

#define L2E 1.44269504088896340736f
#define LN2 0.69314718055994530942f

#define E2(x) __builtin_amdgcn_exp2f(x)     // raw v_exp_f32 (inputs bounded, no denorm guard)
#define LOG2(x) __builtin_amdgcn_logf(x)    // raw v_log_f32
#define RCP(x) __builtin_amdgcn_rcpf(x)

__device__ __forceinline__ unsigned short f2bf(float x) {
  union { float f; uint32_t u; } v; v.f = x;
  uint32_t u = v.u;
  u += 0x7FFFu + ((u >> 16) & 1u);   // RNE
  return (unsigned short)(u >> 16);
}

__device__ __forceinline__ float rng_u(uint32_t id) {
  uint64_t x = (uint64_t)id;
  x += 0x9E3779B97F4A7C15ull;
  x = (x ^ (x >> 30)) * 0xBF58476D1CE4E5B9ull;
  x = (x ^ (x >> 27)) * 0x94D049BB133111EBull;
  x ^= (x >> 31);
  return ((float)(uint32_t)(x >> 40) + 0.5f) * (1.0f / 16777216.0f);
}

// gate scale: i,f,o rows get -log2(e) (sign folded so exp2(acc)=e^{-gate});
// g rows get +2*log2(e) (exp2(acc)=e^{2g}).
__device__ __forceinline__ float gsf(int g) { return (g == 2) ? (2.f * L2E) : (-L2E); }

// W_ext(n,k), n in [0,400): k<100 -> w_hh ; k=100+t -> emb[t].w_ih[n] ; k=110 -> bias ; else 0
__device__ float wval(int n, int k, const float* w_hh, const float* w_ih,
                      const float* emb, const float* b_ih, const float* b_hh) {
  if (k < 100) return w_hh[n * 100 + k];
  if (k < 110) {
    int t = k - 100;
    float s = 0.f;
    for (int m = 0; m < 100; ++m) s += emb[t * 100 + m] * w_ih[n * 100 + m];
    return s;
  }
  if (k == 110) return b_ih[n] + b_hh[n];
  return 0.f;
}

__global__ void prep_kernel(const float* __restrict__ emb, const float* __restrict__ w_ih,
                            const float* __restrict__ w_hh, const float* __restrict__ b_ih,
                            const float* __restrict__ b_hh, const float* __restrict__ w_out,
                            const float* __restrict__ b_out,
                            unsigned short* __restrict__ ws, float* __restrict__ tail,
                            float draws) {
  int id = blockIdx.x * 256 + threadIdx.x;
  if (id == 0) tail[2] = draws;
  if (id >= WS_TOTAL) return;
  float v = 0.f;
  if (id < OFF_NT6) {                       // MAIN: nt<6, kk<3 (pure w_hh, all cols real)
    int frag = id >> 9, w = id & 511, lane = w >> 3, j = w & 7;
    int nt = frag / 12, rem = frag % 12, kk = rem >> 2, g = rem & 3;
    int col = lane & 15, grp = lane >> 4;
    int n = g * 100 + nt * 16 + col;
    int k = kk * 32 + grp * 8 + j;
    v = w_hh[n * 100 + k] * gsf(g);
  } else if (id < OFF_K3) {                 // NT6 compressed: cols 0..3 only
    int t = id - OFF_NT6;
    int frag = t >> 7, w = t & 127, i = w >> 3, j = w & 7;
    int kk = frag >> 2, g = frag & 3;
    int grp = i >> 2, colc = i & 3;
    int n = g * 100 + 96 + colc;
    int k = kk * 32 + grp * 8 + j;
    v = w_hh[n * 100 + k] * gsf(g);
  } else if (id < OFF_ZERO) {               // K3 half-frags: k = 96..111
    int t = id - OFF_K3;
    int frag = t >> 8, w = t & 255, i = w >> 3, j = w & 7;
    int nt = frag >> 2, g = frag & 3;
    int col = i & 15, g2 = i >> 4;
    int nl = nt * 16 + col;
    int k = 96 + g2 * 8 + j;
    v = (nl < 100) ? wval(g * 100 + nl, k, w_hh, w_ih, emb, b_ih, b_hh) * gsf(g) : 0.f;
  } else if (id < WF_TOTAL) {               // zero block
    v = 0.f;
  } else if (id < OFF_WOUT + 1536) {        // Wout kk0..2 (scaled by log2(e))
    int t = id - OFF_WOUT;
    int kk = t >> 9, w = t & 511, lane = w >> 3, j = w & 7;
    int tt = lane & 15, grp = lane >> 4;
    int k = kk * 32 + grp * 8 + j;
    v = (tt < 10) ? w_out[tt * 100 + k] * L2E : 0.f;
  } else {                                  // Wout kk3 half-frag
    int t = id - (OFF_WOUT + 1536);
    int i = t >> 3, j = t & 7;
    int tt = i & 15, g2 = i >> 4;
    int k = 96 + g2 * 8 + j;
    if (tt < 10) {
      if (k < 100) v = w_out[tt * 100 + k] * L2E;
      else if (k == 110) v = b_out[tt] * L2E;
    }
  }
  ws[id] = f2bf(v);
}

__global__ void __launch_bounds__(THREADS, 2)
lstm_kernel(const float* __restrict__ h_t,
            const unsigned short* __restrict__ ws,
            const int* __restrict__ testing_p,
            float* __restrict__ out, float* __restrict__ tail) {
  __shared__ unsigned short Wlds[WF_TOTAL];      // 91152 B, fragment-ordered
  __shared__ unsigned short Hlds[ROWS * HSTR];   // 65536 B, 256B rows, chunk-XOR swizzled

  const int tid = threadIdx.x;
  const int lane = tid & 63;
  const int w = tid >> 6;
  const int col = lane & 15;
  const int grp = lane >> 4;
  const int wrow0 = w * 32;
  const int rowbase0 = blockIdx.x * ROWS;
  const int tst = *testing_p;

  const short8 zv = {0,0,0,0,0,0,0,0};
  const f32x4 z4 = {0.f,0.f,0.f,0.f};

  // ---- stage W fragments (linear copy; frag layout is already conflict-free) ----
  for (int i = tid; i < WF_TOTAL / 8; i += THREADS)
    *(uint4*)&Wlds[i * 8] = ((const uint4*)ws)[i];

  // ---- stage h_t -> bf16, swizzled 256B rows ----
  for (int i = tid; i < ROWS * 25; i += THREADS) {
    int r = i / 25, ch = i % 25;
    const float4 v = *(const float4*)(h_t + (size_t)(rowbase0 + r) * E_ + ch * 4);
    ushort4 pk = make_ushort4(f2bf(v.x), f2bf(v.y), f2bf(v.z), f2bf(v.w));
    *(ushort4*)&Hlds[r * HSTR + (((ch >> 1) ^ (r & 7)) << 3) + (ch & 1) * 4] = pk;
  }
  // ---- onehot(tok=0) + bias init (k=100..111) ----
  if (tid < ROWS) {
    int r = tid;
    *(ushort4*)&Hlds[r * HSTR + ((12 ^ (r & 7)) << 3) + 4] = make_ushort4(0x3F80, 0, 0, 0);
    *(ushort4*)&Hlds[r * HSTR + ((13 ^ (r & 7)) << 3)]     = make_ushort4(0, 0, 0, 0);
    *(ushort4*)&Hlds[r * HSTR + ((13 ^ (r & 7)) << 3) + 4] = make_ushort4(0, 0, 0x3F80, 0);
  }

  // Wout fragments -> registers (global, L2-hot, once)
  short8 bo[4];
#pragma unroll
  for (int kk = 0; kk < 3; ++kk)
    bo[kk] = *(const short8*)(ws + OFF_WOUT + kk * 512 + lane * 8);
  bo[3] = *(const short8*)(ws + OFF_WOUT + 1536 + (lane & 31) * 8);

  __syncthreads();
  // Waves fully independent from here (each owns rows [wrow0, wrow0+32)) — the
  // attn-like regime where s_setprio measured +4-7% (T5/m191).

  auto ldA = [&](int mi, int kk) -> short8 {
    int row = wrow0 + mi * 16 + col;
    int chunk = (kk < 3) ? (kk * 4 + grp) : (12 + (grp & 1));
    short8 v = *(const short8*)&Hlds[row * HSTR + ((chunk ^ (row & 7)) << 3)];
    if (kk == 3 && grp >= 2) v = zv;   // upper K half of last frag must be 0 (B mirrors)
    return v;
  };

  short8 a[2][4];
#pragma unroll
  for (int mi = 0; mi < 2; ++mi)
#pragma unroll
    for (int kk = 0; kk < 3; ++kk) a[mi][kk] = ldA(mi, kk);

  float cst[7][2][4] = {};   // c-state, stored in 2*log2(e) scale
  float ent_acc = 0.f, match_acc = 0.f;

#pragma unroll 1
  for (int step = 0; step < L_; ++step) {
    // onehot chunk changed since last full reload
#pragma unroll
    for (int mi = 0; mi < 2; ++mi) a[mi][3] = ldA(mi, 3);

#pragma unroll
    for (int nt = 0; nt < 7; ++nt) {
      f32x4 acc[4][2];
#pragma unroll
      for (int g = 0; g < 4; ++g)
#pragma unroll
        for (int mi = 0; mi < 2; ++mi) acc[g][mi] = z4;

      __builtin_amdgcn_s_setprio(1);   // favor this wave while its MFMA cluster issues
#pragma unroll
      for (int kk = 0; kk < 3; ++kk) {
        short8 b[4];
#pragma unroll
        for (int g = 0; g < 4; ++g) {
          if (nt < 6) {
            b[g] = *(const short8*)&Wlds[OFF_MAIN + ((nt * 3 + kk) * 4 + g) * 512 + lane * 8];
          } else {
            int addr = (col < 4) ? (OFF_NT6 + (kk * 4 + g) * 128 + (grp * 4 + col) * 8)
                                 : OFF_ZERO;
            b[g] = *(const short8*)&Wlds[addr];
          }
        }
#pragma unroll
        for (int g = 0; g < 4; ++g)
#pragma unroll
          for (int mi = 0; mi < 2; ++mi)
            acc[g][mi] = __builtin_amdgcn_mfma_f32_16x16x32_bf16(a[mi][kk], b[g], acc[g][mi], 0, 0, 0);
      }
      // kk=3 (k=96..111): half-frags, lanes>=32 mirror (A side zeroed)
#pragma unroll
      for (int g = 0; g < 4; ++g) {
        short8 b3 = *(const short8*)&Wlds[OFF_K3 + (nt * 4 + g) * 256 + (lane & 31) * 8];
#pragma unroll
        for (int mi = 0; mi < 2; ++mi)
          acc[g][mi] = __builtin_amdgcn_mfma_f32_16x16x32_bf16(a[mi][3], b3, acc[g][mi], 0, 0, 0);
      }
      __builtin_amdgcn_s_setprio(0);

      // ---- LSTM elementwise, packed f32 pairs across rr (v_pk_* dual-issue) ----
      const int e = nt * 16 + col;
      const bool evalid = (e < 100);
      const pf2 one2 = {1.f, 1.f};
#pragma unroll
      for (int mi = 0; mi < 2; ++mi)
#pragma unroll
        for (int p = 0; p < 2; ++p) {
          const int r0 = 2 * p, r1 = 2 * p + 1;
          pf2 ei, ef, eg, eo, ct;
          ei.x = E2(acc[0][mi][r0]); ei.y = E2(acc[0][mi][r1]);   // e^{-gi}
          ef.x = E2(acc[1][mi][r0]); ef.y = E2(acc[1][mi][r1]);   // e^{-gf}
          eg.x = E2(acc[2][mi][r0]); eg.y = E2(acc[2][mi][r1]);   // e^{2*gg}
          eo.x = E2(acc[3][mi][r0]); eo.y = E2(acc[3][mi][r1]);   // e^{-go}
          ct.x = cst[nt][mi][r0];    ct.y = cst[nt][mi][r1];      // 2*l2e*c
          pf2 pi1 = one2 + ei, pf1 = one2 + ef, eg1 = eg + one2;
          pf2 egm2 = eg * (2.f * L2E) - (2.f * L2E);              // pk_fma: 2*l2e*(eg-1)
          pf2 t1 = pi1 * eg1;
          pf2 num = ct * t1 + egm2 * pf1;                          // pk_mul + pk_fma
          pf2 den = pf1 * t1;
          pf2 cn;
          cn.x = num.x * RCP(den.x); cn.y = num.y * RCP(den.y);    // 2*l2e*c_new
          cst[nt][mi][r0] = cn.x; cst[nt][mi][r1] = cn.y;
          pf2 ec; ec.x = E2(cn.x); ec.y = E2(cn.y);                // e^{2*c_new}
          pf2 d2 = (ec + one2) * (one2 + eo);
          pf2 hn;
          hn.x = (ec.x - 1.f) * RCP(d2.x); hn.y = (ec.y - 1.f) * RCP(d2.y);
          if (evalid) {
            union { __hip_bfloat162 h2; uint32_t u; } cv;
            cv.h2 = __float22bfloat162_rn(make_float2(hn.x, hn.y)); // v_cvt_pk_bf16_f32
            int row0 = wrow0 + mi * 16 + grp * 4 + r0;
            int row1 = row0 + 1;
            Hlds[row0 * HSTR + (((e >> 3) ^ (row0 & 7)) << 3) + (e & 7)] =
                (unsigned short)(cv.u & 0xFFFFu);
            Hlds[row1 * HSTR + (((e >> 3) ^ (row1 & 7)) << 3) + (e & 7)] =
                (unsigned short)(cv.u >> 16);
          }
        }
    } // nt

    // full A reload (serves logits now + next step's gates)
#pragma unroll
    for (int mi = 0; mi < 2; ++mi)
#pragma unroll
      for (int kk = 0; kk < 4; ++kk) a[mi][kk] = ldA(mi, kk);

    __builtin_amdgcn_s_setprio(1);
    f32x4 accl[2] = {z4, z4};
#pragma unroll
    for (int mi = 0; mi < 2; ++mi)
#pragma unroll
      for (int kk = 0; kk < 4; ++kk)
        accl[mi] = __builtin_amdgcn_mfma_f32_16x16x32_bf16(a[mi][kk], bo[kk], accl[mi], 0, 0, 0);
    __builtin_amdgcn_s_setprio(0);

    // logits (log2-scaled) -> H-row spare chunks
    if (col < 10) {
#pragma unroll
      for (int mi = 0; mi < 2; ++mi)
#pragma unroll
        for (int rr = 0; rr < 4; ++rr) {
          int r = wrow0 + mi * 16 + grp * 4 + rr;
          int idx = (col < 8)
              ? (r * HSTR + (((14 + (col >> 2)) ^ (r & 7)) << 3) + (col & 3) * 2)
              : (r * HSTR + ((12 ^ (r & 7)) << 3) + 4 + (col - 8) * 2);
          *(float*)&Hlds[idx] = accl[mi][rr];
        }
    }

    // ---- scalar per-row softmax / argmax / CDF-sample / entropy ----
    if (lane < 32) {
      const int r = wrow0 + lane;
      const int growf = rowbase0 + r;
      float lg[10];
#pragma unroll
      for (int t = 0; t < 8; ++t)
        lg[t] = *(const float*)&Hlds[r * HSTR + (((14 + (t >> 2)) ^ (r & 7)) << 3) + (t & 3) * 2];
#pragma unroll
      for (int t = 8; t < 10; ++t)
        lg[t] = *(const float*)&Hlds[r * HSTR + ((12 ^ (r & 7)) << 3) + 4 + (t - 8) * 2];

      float m = lg[0]; int am = 0;
#pragma unroll
      for (int t = 1; t < 10; ++t) if (lg[t] > m) { m = lg[t]; am = t; }
      float S = 0.f, dp = 0.f;
#pragma unroll
      for (int t = 0; t < 10; ++t) {
        float z = lg[t] - m;              // log2 units
        float ev = E2(z);                 // = e^{true logit - true max}
        lg[t] = ev; S += ev; dp = fmaf(ev, z, dp);
      }
      float rS = RCP(S);
      ent_acc += (LOG2(S) - dp * rS) * LN2;   // ln S - sum(p * z_ln)

      int tok;
      if (tst) tok = am;
      else {
        float u = rng_u((uint32_t)growf * 6u + (uint32_t)step);
        float target = u * S;
        float cum = 0.f; int cnt = 0;
#pragma unroll
        for (int t = 0; t < 9; ++t) { cum += lg[t]; cnt += (cum < target) ? 1 : 0; }
        tok = cnt;
      }
      out[(size_t)growf * L_ + step] = (float)tok;
      match_acc += (tok == am) ? 1.f : 0.f;

      const unsigned short ONE = 0x3F80;
      *(ushort4*)&Hlds[r * HSTR + ((12 ^ (r & 7)) << 3) + 4] =
          make_ushort4(tok==0?ONE:0, tok==1?ONE:0, tok==2?ONE:0, tok==3?ONE:0);
      *(ushort4*)&Hlds[r * HSTR + ((13 ^ (r & 7)) << 3)] =
          make_ushort4(tok==4?ONE:0, tok==5?ONE:0, tok==6?ONE:0, tok==7?ONE:0);
      *(ushort4*)&Hlds[r * HSTR + ((13 ^ (r & 7)) << 3) + 4] =
          make_ushort4(tok==8?ONE:0, tok==9?ONE:0, ONE, 0);
    }
  } // step

  // ---- block reduce: entropy + matches (2 atomics per block) ----
#pragma unroll
  for (int d2 = 1; d2 < 32; d2 <<= 1) {
    ent_acc += __shfl_xor(ent_acc, d2);
    match_acc += __shfl_xor(match_acc, d2);
  }
  __syncthreads();
  float* red = (float*)Hlds;
  if (lane == 0) { red[w * 2] = ent_acc; red[w * 2 + 1] = match_acc; }
  __syncthreads();
  if (tid == 0) {
    float es = 0.f, ms = 0.f;
#pragma unroll
    for (int i = 0; i < 8; ++i) { es += red[i * 2]; ms += red[i * 2 + 1]; }
    atomicAdd(&tail[0], es);
    atomicAdd(&tail[1], ms);
  }
}

extern "C" void kernel_launch(void* const* d_in, const int* in_sizes, int n_in,
                              void* d_out, int out_size, void* d_ws, size_t ws_size,
                              hipStream_t stream) {
  const float* h_t   = (const float*)d_in[0];
  const float* emb   = (const float*)d_in[1];
  const float* w_ih  = (const float*)d_in[2];
  const float* w_hh  = (const float*)d_in[3];
  const float* b_ih  = (const float*)d_in[4];
  const float* b_hh  = (const float*)d_in[5];
  const float* w_out = (const float*)d_in[6];
  const float* b_out = (const float*)d_in[7];
  const int* testing = (const int*)d_in[8];
  float* out = (float*)d_out;
  const int B = in_sizes[0] / E_;
  float* tail = out + (size_t)B * L_;

  unsigned short* ws = (unsigned short*)d_ws;

  hipMemsetAsync(tail, 0, 2 * sizeof(float), stream);

  prep_kernel<<<(WS_TOTAL + 255) / 256, 256, 0, stream>>>(
      emb, w_ih, w_hh, b_ih, b_hh, w_out, b_out, ws, tail,
      (float)((long long)B * L_));

  lstm_kernel<<<B / ROWS, THREADS, 0, stream>>>(h_t, ws, testing, out, tail);
}